// Round 10
// baseline (399.202 us; speedup 1.0000x reference)
//
#include <hip/hip_runtime.h>

// Problem constants (fixed by the reference)
#define NN 200000   // nodes
#define CC 256      // channels
#define NG 512      // graphs/segments
#define NBF 1562    // full 128-node blocks (1562*128 = 199936; +1 tail block)

typedef __attribute__((ext_vector_type(8))) __bf16 bf16x8;
typedef __attribute__((ext_vector_type(16))) float f32x16;

typedef unsigned short u16;

#define VWAITN(n) asm volatile("s_waitcnt vmcnt(%0)" :: "i"(n) : "memory")
#define SBAR() __builtin_amdgcn_s_barrier()
#define SCHED() __builtin_amdgcn_sched_barrier(0)

__device__ __forceinline__ u16 f2bf(float f) {
  union { float f; unsigned u; } v; v.f = f;
  unsigned u = v.u;
  u += 0x7fffu + ((u >> 16) & 1u);   // RNE
  return (u16)(u >> 16);
}
__device__ __forceinline__ unsigned pack2(float a, float b) {
  return (unsigned)f2bf(a) | ((unsigned)f2bf(b) << 16);
}
__device__ __forceinline__ float bflo(unsigned u){ union{unsigned u; float f;} x; x.u = u << 16; return x.f; }
__device__ __forceinline__ float bfhi(unsigned u){ union{unsigned u; float f;} x; x.u = u & 0xffff0000u; return x.f; }

// ---------------------------------------------------------------------------
// K0: prep weights into 32x32x16 MFMA A-operand fragment slices (16 KB each).
//  Slice order: 0..3 K-even, 4..7 Q-even, 8..11 K-odd, 12..15 Q-odd,
//  16..23 V, 24..31 Wo.  (unchanged — numerically proven)
// ---------------------------------------------------------------------------
__global__ __launch_bounds__(256) void prep_kernel(
    const float* __restrict__ Wq, const float* __restrict__ Wk,
    const float* __restrict__ Wv, const float* __restrict__ Wo,
    u16* __restrict__ Wall) {
  int idx = blockIdx.x * 256 + threadIdx.x;     // 0..262143
  int s = idx >> 13;
  int inner = idx & 8191;
  int ks = inner >> 9;
  int l = (inner >> 3) & 63;
  int j = inner & 7;
  int r = l & 31, hi5 = l >> 5;
  int k = ks * 16 + hi5 * 8 + j;
  const float* W; int c0;
  if (s < 16) {
    int p = s >> 3, r4 = s & 7;
    if (r4 < 4) { W = Wk; c0 = r4 * 64 + p * 32; }
    else        { W = Wq; c0 = (r4 - 4) * 64 + p * 32; }
  } else if (s < 24) { W = Wv; c0 = (s - 16) * 32; }
  else               { W = Wo; c0 = (s - 24) * 32; }
  Wall[idx] = f2bf(W[k * 256 + c0 + r]);
}

// ---------------------------------------------------------------------------
// K1: segment boundaries from sorted batch.
// ---------------------------------------------------------------------------
__global__ __launch_bounds__(256) void seg_bounds_kernel(
    const int* __restrict__ batch, int* __restrict__ seg_start, int n) {
  int i = blockIdx.x * 256 + threadIdx.x;
  if (i >= n) return;
  int a = batch[i];
  int b = (i + 1 < n) ? batch[i + 1] : NG;
  for (int g = a + 1; g <= b; ++g) seg_start[g] = i + 1;
  if (i == 0) for (int g = 0; g <= a; ++g) seg_start[g] = 0;
}

// ---------------------------------------------------------------------------
// Stage one 16 KB W slice into LDS: 4 waves x 4 reps x 64 lanes x 16 B.
// 4 global_load_lds per wave -> vmcnt +4 per staged slice per wave.
// ---------------------------------------------------------------------------
__device__ __forceinline__ void stage_slice(
    const u16* __restrict__ Wall, u16* dst_base, int s, int w, int lane) {
#pragma unroll
  for (int rep = 0; rep < 4; ++rep) {
    const u16* src = Wall + (size_t)s * 8192 + ((w * 4 + rep) * 64 + lane) * 8;
    u16* dst = dst_base + (w * 4 + rep) * 512;
    __builtin_amdgcn_global_load_lds(
        (const __attribute__((address_space(1))) void*)src,
        (__attribute__((address_space(3))) void*)dst, 16, 0, 0);
  }
}

// ---------------------------------------------------------------------------
// One 32(dims)x32(nodes) slice over K=256: A-frags from LDS (16 ds_read_b128),
// B (x) from registers.  Single acc chain (16 regs) to ease register pressure.
// ---------------------------------------------------------------------------
__device__ __forceinline__ f32x16 gemm_lds(
    const u16* buf, const bf16x8 xfr[16], int lane) {
  f32x16 acc = {0.f,0.f,0.f,0.f,0.f,0.f,0.f,0.f,0.f,0.f,0.f,0.f,0.f,0.f,0.f,0.f};
#pragma unroll
  for (int ks = 0; ks < 16; ++ks) {
    bf16x8 f0 = *reinterpret_cast<const bf16x8*>(&buf[(ks * 64 + lane) * 8]);
    acc = __builtin_amdgcn_mfma_f32_32x32x16_bf16(f0, xfr[ks], acc, 0, 0, 0);
  }
  return acc;
}

// ---------------------------------------------------------------------------
// K2 body.  TAIL=false: all nodes valid, unconditional uniform stores, exact
// counted vmcnt.  TAIL=true: guards + vmcnt(0) drains (counts irrelevant).
// Pipeline: 3 LDS buffers, 2-slice-deep prefetch, 1 barrier per slice:
//   VWAIT(N); s_barrier; sched(0); stage(sl+2); gemm(sl); epilogue.
// ---------------------------------------------------------------------------
template<bool TAIL>
__device__ __forceinline__ void qkv_body(
    const float* __restrict__ x, const u16* __restrict__ Wall,
    const float* __restrict__ bq, const float* __restrict__ bk,
    const float* __restrict__ bv, u16* __restrict__ v_out,
    float* __restrict__ scores, u16 (*Wbuf)[8192], int base) {
  const int t = threadIdx.x;
  const int w = t >> 6, lane = t & 63;
  const int col = lane & 31, hi5 = lane >> 5;
  const int n = base + w * 32 + col;
  const int nl = TAIL ? ((n < NN) ? n : (NN - 1)) : n;
  const bool valid = TAIL ? (n < NN) : true;

  // ---- B-frags: x^T, persistent (64 VGPR). frag kb: k = kb*16+hi5*8+j ----
  bf16x8 xfr[16];
#pragma unroll
  for (int kb = 0; kb < 16; ++kb) {
    const float* px = x + (size_t)nl * CC + kb * 16 + hi5 * 8;
    float4 a0 = *reinterpret_cast<const float4*>(px);
    float4 a1 = *reinterpret_cast<const float4*>(px + 4);
    uint4 u = {pack2(a0.x, a0.y), pack2(a0.z, a0.w),
               pack2(a1.x, a1.y), pack2(a1.z, a1.w)};
    xfr[kb] = *reinterpret_cast<bf16x8*>(&u);
  }
  SCHED();
  stage_slice(Wall, Wbuf[0], 0, w, lane);
  SCHED();
  stage_slice(Wall, Wbuf[1], 1, w, lane);
  SCHED();

  float sp[16];
#pragma unroll
  for (int i = 0; i < 16; ++i) sp[i] = 0.f;

  // ---- K/Q: slices 0..15 (compile-time sl via full unroll) ----
#pragma unroll
  for (int p = 0; p < 2; ++p) {
    unsigned kph[4][8];          // k packed bf16, head g, this half
#pragma unroll
    for (int g = 0; g < 4; ++g) {
      const int sl = p * 8 + g;
      if constexpr (TAIL) { VWAITN(0); } else { VWAITN(4); }
      SBAR(); SCHED();
      stage_slice(Wall, Wbuf[(sl + 2) % 3], sl + 2, w, lane);
      SCHED();
      f32x16 acc = gemm_lds(Wbuf[sl % 3], xfr, lane);
#pragma unroll
      for (int q = 0; q < 4; ++q) {
        float4 b4 = *reinterpret_cast<const float4*>(
            bk + g * 64 + p * 32 + q * 8 + hi5 * 4);
        kph[g][q * 2]     = pack2(acc[4 * q] + b4.x, acc[4 * q + 1] + b4.y);
        kph[g][q * 2 + 1] = pack2(acc[4 * q + 2] + b4.z, acc[4 * q + 3] + b4.w);
      }
    }
#pragma unroll
    for (int h = 0; h < 4; ++h) {
      const int sl = p * 8 + 4 + h;
      if constexpr (TAIL) { VWAITN(0); } else { VWAITN(4); }
      SBAR(); SCHED();
      stage_slice(Wall, Wbuf[(sl + 2) % 3], sl + 2, w, lane);
      SCHED();
      f32x16 acc = gemm_lds(Wbuf[sl % 3], xfr, lane);
#pragma unroll
      for (int q = 0; q < 4; ++q) {
        float4 b4 = *reinterpret_cast<const float4*>(
            bq + h * 64 + p * 32 + q * 8 + hi5 * 4);
        float q0 = acc[4 * q] + b4.x, q1 = acc[4 * q + 1] + b4.y;
        float q2 = acc[4 * q + 2] + b4.z, q3 = acc[4 * q + 3] + b4.w;
#pragma unroll
        for (int g = 0; g < 4; ++g) {
          unsigned k01 = kph[g][q * 2];
          unsigned k23 = kph[g][q * 2 + 1];
          sp[h * 4 + g] += q0 * bflo(k01) + q1 * bfhi(k01) +
                           q2 * bflo(k23) + q3 * bfhi(k23);
        }
      }
    }
  }

  // ---- scores: reduce + store (uniform: both lane-halves write same) ----
#pragma unroll
  for (int i = 0; i < 16; ++i) sp[i] += __shfl_xor(sp[i], 32, 64);
  if (!TAIL || valid) {
#pragma unroll
    for (int q = 0; q < 4; ++q) {
      float4 o = {sp[q * 4] * 0.125f, sp[q * 4 + 1] * 0.125f,
                  sp[q * 4 + 2] * 0.125f, sp[q * 4 + 3] * 0.125f};
      *reinterpret_cast<float4*>(scores + (size_t)n * 16 + q * 4) = o;
    }
  }

  // ---- V: slices 16..23 ----
#pragma unroll
  for (int sv = 0; sv < 8; ++sv) {
    const int sl = 16 + sv;
    // outstanding newer than stage(sl):  sv0: stage17+4scoreStores = 8;
    // sv1..6: stores(sl-2)+stage(sl+1)+stores(sl-1) = 12;  sv7: 2x stores = 8.
    if constexpr (TAIL) { VWAITN(0); }
    else if (sv == 0)   { VWAITN(8); }
    else if (sv == 7)   { VWAITN(8); }
    else                { VWAITN(12); }
    SBAR(); SCHED();
    if (sv < 6) stage_slice(Wall, Wbuf[(sl + 2) % 3], sl + 2, w, lane);
    SCHED();
    f32x16 acc = gemm_lds(Wbuf[sl % 3], xfr, lane);
    if (!TAIL || valid) {
#pragma unroll
      for (int q = 0; q < 4; ++q) {
        int d0 = sv * 32 + q * 8 + hi5 * 4;
        float4 b4 = *reinterpret_cast<const float4*>(bv + d0);
        uint2 pk = {pack2(acc[4 * q] + b4.x, acc[4 * q + 1] + b4.y),
                    pack2(acc[4 * q + 2] + b4.z, acc[4 * q + 3] + b4.w)};
        *reinterpret_cast<uint2*>(v_out + (size_t)n * CC + d0) = pk;
      }
    }
  }
}

__global__ __launch_bounds__(256, 2) void qkv_scores_kernel(
    const float* __restrict__ x, const u16* __restrict__ Wall,
    const float* __restrict__ bq, const float* __restrict__ bk,
    const float* __restrict__ bv, u16* __restrict__ v_out,
    float* __restrict__ scores) {
  __shared__ u16 Wbuf[3][8192];
  if (blockIdx.x != NBF)
    qkv_body<false>(x, Wall, bq, bk, bv, v_out, scores, Wbuf, blockIdx.x * 128);
  else
    qkv_body<true>(x, Wall, bq, bk, bv, v_out, scores, Wbuf, NBF * 128);
}

// ---------------------------------------------------------------------------
// K3: per-segment max & exp-sum over the 16 score columns (block per segment).
// ---------------------------------------------------------------------------
__global__ __launch_bounds__(256) void seg_softmax_kernel(
    const float* __restrict__ scores, const int* __restrict__ seg_start,
    float* __restrict__ seg_max, float* __restrict__ seg_sum) {
  __shared__ float red[256];
  int g = blockIdx.x;
  int s = seg_start[g], e = seg_start[g + 1];
  int t = threadIdx.x;
  int col = t & 15, sub = t >> 4;

  float m = -INFINITY;
  for (int i = s + sub; i < e; i += 16)
    m = fmaxf(m, scores[(size_t)i * 16 + col]);
  red[t] = m;
  __syncthreads();
  for (int step = 8; step >= 1; step >>= 1) {
    if (sub < step) red[t] = fmaxf(red[t], red[t + step * 16]);
    __syncthreads();
  }
  if (t < 16) seg_max[g * 16 + t] = red[t];
  float mcol = red[col];
  __syncthreads();

  float sum = 0.f;
  for (int i = s + sub; i < e; i += 16)
    sum += expf(scores[(size_t)i * 16 + col] - mcol);
  red[t] = sum;
  __syncthreads();
  for (int step = 8; step >= 1; step >>= 1) {
    if (sub < step) red[t] += red[t + step * 16];
    __syncthreads();
  }
  if (t < 16) seg_sum[g * 16 + t] = red[t];
}

// ---------------------------------------------------------------------------
// K4 body: att + att.v + output GEMM (+bo) + att_mean, same pipeline shape.
// ---------------------------------------------------------------------------
template<bool TAIL>
__device__ __forceinline__ void out_body(
    const u16* __restrict__ v_bf, const float* __restrict__ scores,
    const int* __restrict__ batch, const float* __restrict__ seg_max,
    const float* __restrict__ seg_sum, const u16* __restrict__ Wall,
    const float* __restrict__ bo, float* __restrict__ out,
    float* __restrict__ att_mean, u16 (*Wbuf)[8192], int base) {
  const int t = threadIdx.x;
  const int w = t >> 6, lane = t & 63;
  const int col = lane & 31, hi5 = lane >> 5;
  const int n = base + w * 32 + col;
  const int nl = TAIL ? ((n < NN) ? n : (NN - 1)) : n;
  const bool valid = TAIL ? (n < NN) : true;

  // ---- att[16] ----
  int b = batch[nl];
  float att[16];
#pragma unroll
  for (int q = 0; q < 4; ++q) {
    float4 sc = *reinterpret_cast<const float4*>(scores + (size_t)nl * 16 + q * 4);
    float4 mx = *reinterpret_cast<const float4*>(seg_max + b * 16 + q * 4);
    float4 sm = *reinterpret_cast<const float4*>(seg_sum + b * 16 + q * 4);
    att[q * 4 + 0] = expf(sc.x - mx.x) / (sm.x + 1e-16f);
    att[q * 4 + 1] = expf(sc.y - mx.y) / (sm.y + 1e-16f);
    att[q * 4 + 2] = expf(sc.z - mx.z) / (sm.z + 1e-16f);
    att[q * 4 + 3] = expf(sc.w - mx.w) / (sm.w + 1e-16f);
  }

  uint4 vv[4][4];   // v row, packed bf16: [g][dw]
#pragma unroll
  for (int g = 0; g < 4; ++g)
#pragma unroll
    for (int dw = 0; dw < 4; ++dw)
      vv[g][dw] = *reinterpret_cast<const uint4*>(
          v_bf + (size_t)nl * CC + g * 64 + dw * 16 + hi5 * 8);

  // att_mean: uniform store (both halves write identical value), pre-stage.
  if (!TAIL || valid) {
    float4 am;
    am.x = 0.25f * (att[0] + att[4] + att[8] + att[12]);
    am.y = 0.25f * (att[1] + att[5] + att[9] + att[13]);
    am.z = 0.25f * (att[2] + att[6] + att[10] + att[14]);
    am.w = 0.25f * (att[3] + att[7] + att[11] + att[15]);
    *reinterpret_cast<float4*>(att_mean + (size_t)n * 4) = am;
  }
  SCHED();
  stage_slice(Wall, Wbuf[0], 24, w, lane);
  SCHED();
  stage_slice(Wall, Wbuf[1], 25, w, lane);
  SCHED();

  // ---- oa^T B-frags ----
  bf16x8 oaf[16];
#pragma unroll
  for (int dw = 0; dw < 4; ++dw) {
    float vr[4][8];
#pragma unroll
    for (int g = 0; g < 4; ++g) {
      uint4 u4 = vv[g][dw];
      vr[g][0] = bflo(u4.x); vr[g][1] = bfhi(u4.x);
      vr[g][2] = bflo(u4.y); vr[g][3] = bfhi(u4.y);
      vr[g][4] = bflo(u4.z); vr[g][5] = bfhi(u4.z);
      vr[g][6] = bflo(u4.w); vr[g][7] = bfhi(u4.w);
    }
#pragma unroll
    for (int h = 0; h < 4; ++h) {
      unsigned res[4];
#pragma unroll
      for (int jj = 0; jj < 4; ++jj) {
        float lo = att[h * 4 + 0] * vr[0][2 * jj] + att[h * 4 + 1] * vr[1][2 * jj] +
                   att[h * 4 + 2] * vr[2][2 * jj] + att[h * 4 + 3] * vr[3][2 * jj];
        float hf = att[h * 4 + 0] * vr[0][2 * jj + 1] + att[h * 4 + 1] * vr[1][2 * jj + 1] +
                   att[h * 4 + 2] * vr[2][2 * jj + 1] + att[h * 4 + 3] * vr[3][2 * jj + 1];
        res[jj] = pack2(lo, hf);
      }
      uint4 u = {res[0], res[1], res[2], res[3]};
      oaf[h * 4 + dw] = *reinterpret_cast<bf16x8*>(&u);
    }
  }

  // ---- output GEMM: slices 24..31 ----
#pragma unroll
  for (int so = 0; so < 8; ++so) {
    // newer than stage(24+so): so0: stage25 = 4;  so1: stage26+stores0 = 8;
    // so2..6: stores(so-2)+stage(so+25)+stores(so-1) = 12;  so7: 2x stores = 8.
    if constexpr (TAIL) { VWAITN(0); }
    else if (so == 0)   { VWAITN(4); }
    else if (so == 1)   { VWAITN(8); }
    else if (so == 7)   { VWAITN(8); }
    else                { VWAITN(12); }
    SBAR(); SCHED();
    if (so < 6) stage_slice(Wall, Wbuf[(so + 2) % 3], 26 + so, w, lane);
    SCHED();
    f32x16 acc = gemm_lds(Wbuf[so % 3], oaf, lane);
    if (!TAIL || valid) {
#pragma unroll
      for (int q = 0; q < 4; ++q) {
        int c0 = so * 32 + q * 8 + hi5 * 4;
        float4 b4 = *reinterpret_cast<const float4*>(bo + c0);
        float4 o = {acc[4 * q] + b4.x, acc[4 * q + 1] + b4.y,
                    acc[4 * q + 2] + b4.z, acc[4 * q + 3] + b4.w};
        *reinterpret_cast<float4*>(out + (size_t)n * CC + c0) = o;
      }
    }
  }
}

__global__ __launch_bounds__(256, 2) void out_kernel(
    const u16* __restrict__ v_bf, const float* __restrict__ scores,
    const int* __restrict__ batch, const float* __restrict__ seg_max,
    const float* __restrict__ seg_sum, const u16* __restrict__ Wall,
    const float* __restrict__ bo, float* __restrict__ out,
    float* __restrict__ att_mean) {
  __shared__ u16 Wbuf[3][8192];
  if (blockIdx.x != NBF)
    out_body<false>(v_bf, scores, batch, seg_max, seg_sum, Wall, bo, out,
                    att_mean, Wbuf, blockIdx.x * 128);
  else
    out_body<true>(v_bf, scores, batch, seg_max, seg_sum, Wall, bo, out,
                   att_mean, Wbuf, NBF * 128);
}

// ---------------------------------------------------------------------------
extern "C" void kernel_launch(void* const* d_in, const int* in_sizes, int n_in,
                              void* d_out, int out_size, void* d_ws, size_t ws_size,
                              hipStream_t stream) {
  const float* x  = (const float*)d_in[0];
  const int* batch = (const int*)d_in[1];
  const float* Wq = (const float*)d_in[2];
  const float* bq = (const float*)d_in[3];
  const float* Wk = (const float*)d_in[4];
  const float* bk = (const float*)d_in[5];
  const float* Wv = (const float*)d_in[6];
  const float* bv = (const float*)d_in[7];
  const float* Wo = (const float*)d_in[8];
  const float* bo = (const float*)d_in[9];

  char* ws = (char*)d_ws;
  u16*   Wall      = (u16*)ws;                               //   524,288 B (32 slices)
  int*   seg_start = (int*)(ws + 524288);                    //     2,052 B
  float* seg_max   = (float*)(ws + 528384);                  //    32,768 B
  float* seg_sum   = (float*)(ws + 561152);                  //    32,768 B
  float* scores    = (float*)(ws + 593920);                  // 12,800,000 B
  u16*   v_bf      = (u16*)(ws + 13393920);                  // 102,400,000 B

  float* out = (float*)d_out;
  float* att_mean = out + (size_t)NN * CC;

  const int NB = NBF + 1;   // 1562 full blocks + 1 tail block (64 nodes)

  prep_kernel<<<1024, 256, 0, stream>>>(Wq, Wk, Wv, Wo, Wall);
  seg_bounds_kernel<<<(NN + 255) / 256, 256, 0, stream>>>(batch, seg_start, NN);
  qkv_scores_kernel<<<NB, 256, 0, stream>>>(x, Wall, bq, bk, bv, v_bf, scores);
  seg_softmax_kernel<<<NG, 256, 0, stream>>>(scores, seg_start, seg_max, seg_sum);
  out_kernel<<<NB, 256, 0, stream>>>(v_bf, scores, batch, seg_max, seg_sum,
                                     Wall, bo, out, att_mean);
}

// Round 11
// 320.269 us; speedup vs baseline: 1.2465x; 1.2465x over previous
//
#include <hip/hip_runtime.h>

// Problem constants (fixed by the reference)
#define NN 200000   // nodes
#define CC 256      // channels
#define NG 512      // graphs/segments

typedef __attribute__((ext_vector_type(8))) __bf16 bf16x8;
typedef __attribute__((ext_vector_type(16))) float f32x16;
typedef unsigned short u16;

__device__ __forceinline__ u16 f2bf(float f) {
  union { float f; unsigned u; } v; v.f = f;
  unsigned u = v.u;
  u += 0x7fffu + ((u >> 16) & 1u);   // RNE
  return (u16)(u >> 16);
}
__device__ __forceinline__ unsigned pack2(float a, float b) {
  return (unsigned)f2bf(a) | ((unsigned)f2bf(b) << 16);
}
__device__ __forceinline__ float bflo(unsigned u){ union{unsigned u; float f;} x; x.u = u << 16; return x.f; }
__device__ __forceinline__ float bfhi(unsigned u){ union{unsigned u; float f;} x; x.u = u & 0xffff0000u; return x.f; }

// ---------------------------------------------------------------------------
// K0: prep weights into 32x32x16 MFMA A-operand fragment slices (16 KB each).
//  Slice order: 0..3 K-even, 4..7 Q-even, 8..11 K-odd, 12..15 Q-odd,
//  16..23 V, 24..31 Wo.  (unchanged — numerically proven)
// ---------------------------------------------------------------------------
__global__ __launch_bounds__(256) void prep_kernel(
    const float* __restrict__ Wq, const float* __restrict__ Wk,
    const float* __restrict__ Wv, const float* __restrict__ Wo,
    u16* __restrict__ Wall) {
  int idx = blockIdx.x * 256 + threadIdx.x;     // 0..262143
  int s = idx >> 13;
  int inner = idx & 8191;
  int ks = inner >> 9;
  int l = (inner >> 3) & 63;
  int j = inner & 7;
  int r = l & 31, hi5 = l >> 5;
  int k = ks * 16 + hi5 * 8 + j;
  const float* W; int c0;
  if (s < 16) {
    int p = s >> 3, r4 = s & 7;
    if (r4 < 4) { W = Wk; c0 = r4 * 64 + p * 32; }
    else        { W = Wq; c0 = (r4 - 4) * 64 + p * 32; }
  } else if (s < 24) { W = Wv; c0 = (s - 16) * 32; }
  else               { W = Wo; c0 = (s - 24) * 32; }
  Wall[idx] = f2bf(W[k * 256 + c0 + r]);
}

// ---------------------------------------------------------------------------
// K1: segment boundaries from sorted batch.
// ---------------------------------------------------------------------------
__global__ __launch_bounds__(256) void seg_bounds_kernel(
    const int* __restrict__ batch, int* __restrict__ seg_start, int n) {
  int i = blockIdx.x * 256 + threadIdx.x;
  if (i >= n) return;
  int a = batch[i];
  int b = (i + 1 < n) ? batch[i + 1] : NG;
  for (int g = a + 1; g <= b; ++g) seg_start[g] = i + 1;
  if (i == 0) for (int g = 0; g <= a; ++g) seg_start[g] = 0;
}

// ---------------------------------------------------------------------------
// Stage one 16 KB W slice into LDS: 4 waves x 4 reps x 64 lanes x 16 B.
// ---------------------------------------------------------------------------
__device__ __forceinline__ void stage_slice(
    const u16* __restrict__ Wall, u16* dst_base, int s, int w, int lane) {
#pragma unroll
  for (int rep = 0; rep < 4; ++rep) {
    const u16* src = Wall + (size_t)s * 8192 + ((w * 4 + rep) * 64 + lane) * 8;
    u16* dst = dst_base + (w * 4 + rep) * 512;
    __builtin_amdgcn_global_load_lds(
        (const __attribute__((address_space(1))) void*)src,
        (__attribute__((address_space(3))) void*)dst, 16, 0, 0);
  }
}

// ---------------------------------------------------------------------------
// One 32(dims)x32(nodes) slice over K=256: A-frags from LDS (16 ds_read_b128),
// B (x) from registers.  Dual accumulator chains (R7-proven).
// ---------------------------------------------------------------------------
__device__ __forceinline__ f32x16 gemm_lds(
    const u16* buf, const bf16x8 xfr[16], int lane) {
  f32x16 a0 = {0.f,0.f,0.f,0.f,0.f,0.f,0.f,0.f,0.f,0.f,0.f,0.f,0.f,0.f,0.f,0.f};
  f32x16 a1 = a0;
#pragma unroll
  for (int ks = 0; ks < 16; ks += 2) {
    bf16x8 f0 = *reinterpret_cast<const bf16x8*>(&buf[(ks * 64 + lane) * 8]);
    bf16x8 f1 = *reinterpret_cast<const bf16x8*>(&buf[((ks + 1) * 64 + lane) * 8]);
    a0 = __builtin_amdgcn_mfma_f32_32x32x16_bf16(f0, xfr[ks], a0, 0, 0, 0);
    a1 = __builtin_amdgcn_mfma_f32_32x32x16_bf16(f1, xfr[ks + 1], a1, 0, 0, 0);
  }
  return a0 + a1;
}

// ---------------------------------------------------------------------------
// K2: fused QKV + scores.  4 waves x 32 nodes = 128 nodes/block.
//  Scatter-free: x staged coalesced->LDS frag layout; V bounced through LDS
//  to slice-major v_bf (contiguous 8 KB stores); biases in LDS.
// ---------------------------------------------------------------------------
__global__ __launch_bounds__(256, 2) void qkv_scores_kernel(
    const float* __restrict__ x, const u16* __restrict__ Wall,
    const float* __restrict__ bq, const float* __restrict__ bk,
    const float* __restrict__ bv,
    u16* __restrict__ v_bf,               // slice-major: [(sv*NN + n)*32 + d]
    float* __restrict__ scores) {         // [NN][16]
  __shared__ __align__(16) char smem[65536];
  u16* xs = (u16*)smem;                          // phase A: 64 KB x frag tile
  u16 (*Wbuf)[8192] = (u16(*)[8192])smem;        // phase B: 2 x 16 KB
  u16* Vst = (u16*)(smem + 32768);               // 2 x 5120 shorts (128 x 40)
  float* biasL = (float*)(smem + 53248);         // [bk 0..255 | bq | bv]

  const int t = threadIdx.x;
  const int w = t >> 6, lane = t & 63;
  const int col = lane & 31, hi5 = lane >> 5;
  const int r0 = blockIdx.x * 128;
  const int node = w * 32 + col;
  const int n = r0 + node;
  const bool valid = (n < NN);

  // ---- stage x: coalesced fp32 reads -> bf16 -> swizzled frag layout ----
#pragma unroll
  for (int i = 0; i < 16; ++i) {
    int u = i * 256 + t;
    int r = u >> 5, c8 = (u & 31) * 8;
    int gr = r0 + r; if (gr >= NN) gr = NN - 1;
    const float* px = x + (size_t)gr * CC + c8;
    float4 a0 = *(const float4*)px;
    float4 a1 = *(const float4*)(px + 4);
    uint4 pk = {pack2(a0.x, a0.y), pack2(a0.z, a0.w),
                pack2(a1.x, a1.y), pack2(a1.z, a1.w)};
    int kb = c8 >> 4, hi = (c8 >> 3) & 1;
    int lp = (hi * 32 + (r & 31)) ^ kb;
    *(uint4*)&xs[(((r >> 5) * 16 + kb) * 64 + lp) * 8] = pk;
  }
  __syncthreads();

  bf16x8 xfr[16];
#pragma unroll
  for (int kb = 0; kb < 16; ++kb)
    xfr[kb] = *(const bf16x8*)&xs[((w * 16 + kb) * 64 + (lane ^ kb)) * 8];
  __syncthreads();                               // xs dead; overlay safe

  stage_slice(Wall, Wbuf[0], 0, w, lane);
  biasL[t] = bk[t];
  biasL[256 + t] = bq[t];
  biasL[512 + t] = bv[t];
  __syncthreads();                               // drains stage0 + bias writes

  float sp[16];
#pragma unroll
  for (int i = 0; i < 16; ++i) sp[i] = 0.f;

  // ---- K/Q: slices 0..15, p-split fold (R7-proven) ----
#pragma unroll
  for (int p = 0; p < 2; ++p) {
    unsigned kph[4][8];
#pragma unroll
    for (int g = 0; g < 4; ++g) {
      const int sl = p * 8 + g;
      stage_slice(Wall, Wbuf[(sl + 1) & 1], sl + 1, w, lane);
      f32x16 acc = gemm_lds(Wbuf[sl & 1], xfr, lane);
#pragma unroll
      for (int q = 0; q < 4; ++q) {
        float4 b4 = *(const float4*)&biasL[g * 64 + p * 32 + q * 8 + hi5 * 4];
        kph[g][q * 2]     = pack2(acc[4*q] + b4.x, acc[4*q+1] + b4.y);
        kph[g][q * 2 + 1] = pack2(acc[4*q+2] + b4.z, acc[4*q+3] + b4.w);
      }
      __syncthreads();
    }
#pragma unroll
    for (int h = 0; h < 4; ++h) {
      const int sl = p * 8 + 4 + h;
      stage_slice(Wall, Wbuf[(sl + 1) & 1], sl + 1, w, lane);
      f32x16 acc = gemm_lds(Wbuf[sl & 1], xfr, lane);
#pragma unroll
      for (int q = 0; q < 4; ++q) {
        float4 b4 = *(const float4*)&biasL[256 + h * 64 + p * 32 + q * 8 + hi5 * 4];
        float q0 = acc[4*q] + b4.x, q1 = acc[4*q+1] + b4.y;
        float q2 = acc[4*q+2] + b4.z, q3 = acc[4*q+3] + b4.w;
#pragma unroll
        for (int g = 0; g < 4; ++g) {
          unsigned k01 = kph[g][q * 2], k23 = kph[g][q * 2 + 1];
          sp[h*4+g] += q0 * bflo(k01) + q1 * bfhi(k01) +
                       q2 * bflo(k23) + q3 * bfhi(k23);
        }
      }
      __syncthreads();
    }
  }

  // ---- scores reduce + store ----
#pragma unroll
  for (int i = 0; i < 16; ++i) sp[i] += __shfl_xor(sp[i], 32, 64);
  if (hi5 == 0 && valid) {
#pragma unroll
    for (int q = 0; q < 4; ++q) {
      float4 o = {sp[q*4] * 0.125f, sp[q*4+1] * 0.125f,
                  sp[q*4+2] * 0.125f, sp[q*4+3] * 0.125f};
      *(float4*)(scores + (size_t)n * 16 + q * 4) = o;
    }
  }

  // ---- V: slices 16..23 -> Vst bounce -> coalesced slice-major stores ----
#pragma unroll
  for (int sv = 0; sv < 8; ++sv) {
    if (sv < 7) stage_slice(Wall, Wbuf[(sv + 1) & 1], 17 + sv, w, lane);
    f32x16 acc = gemm_lds(Wbuf[sv & 1], xfr, lane);
    u16* vb = Vst + (sv & 1) * 5120;
#pragma unroll
    for (int q = 0; q < 4; ++q) {
      float4 b4 = *(const float4*)&biasL[512 + sv * 32 + q * 8 + hi5 * 4];
      uint2 pk = {pack2(acc[4*q] + b4.x, acc[4*q+1] + b4.y),
                  pack2(acc[4*q+2] + b4.z, acc[4*q+3] + b4.w)};
      *(uint2*)&vb[node * 40 + q * 8 + hi5 * 4] = pk;
    }
    __syncthreads();
    {
      int rr = t >> 1, h2 = t & 1;
      uint4 d0 = *(const uint4*)&vb[rr * 40 + h2 * 16];
      uint4 d1 = *(const uint4*)&vb[rr * 40 + h2 * 16 + 8];
      int gn = r0 + rr;
      if (gn < NN) {
        u16* dst = v_bf + ((size_t)sv * NN + gn) * 32 + h2 * 16;
        *(uint4*)dst = d0;
        *(uint4*)(dst + 8) = d1;
      }
    }
  }
}

// ---------------------------------------------------------------------------
// K3: per-segment max & exp-sum over the 16 score columns (block per segment).
// ---------------------------------------------------------------------------
__global__ __launch_bounds__(256) void seg_softmax_kernel(
    const float* __restrict__ scores, const int* __restrict__ seg_start,
    float* __restrict__ seg_max, float* __restrict__ seg_sum) {
  __shared__ float red[256];
  int g = blockIdx.x;
  int s = seg_start[g], e = seg_start[g + 1];
  int t = threadIdx.x;
  int col = t & 15, sub = t >> 4;

  float m = -INFINITY;
  for (int i = s + sub; i < e; i += 16)
    m = fmaxf(m, scores[(size_t)i * 16 + col]);
  red[t] = m;
  __syncthreads();
  for (int step = 8; step >= 1; step >>= 1) {
    if (sub < step) red[t] = fmaxf(red[t], red[t + step * 16]);
    __syncthreads();
  }
  if (t < 16) seg_max[g * 16 + t] = red[t];
  float mcol = red[col];
  __syncthreads();

  float sum = 0.f;
  for (int i = s + sub; i < e; i += 16)
    sum += expf(scores[(size_t)i * 16 + col] - mcol);
  red[t] = sum;
  __syncthreads();
  for (int step = 8; step >= 1; step >>= 1) {
    if (sub < step) red[t] += red[t + step * 16];
    __syncthreads();
  }
  if (t < 16) seg_sum[g * 16 + t] = red[t];
}

// ---------------------------------------------------------------------------
// K4: fused att + att.v + output GEMM (+bo) + att_mean.
//  Scatter-free: v loaded coalesced (slice-major) -> LDS; out bounced through
//  LDS -> full-line coalesced stores; bo in LDS.
// ---------------------------------------------------------------------------
__global__ __launch_bounds__(256, 2) void out_kernel(
    const u16* __restrict__ v_bf, const float* __restrict__ scores,
    const int* __restrict__ batch, const float* __restrict__ seg_max,
    const float* __restrict__ seg_sum, const u16* __restrict__ Wall,
    const float* __restrict__ bo, float* __restrict__ out,
    float* __restrict__ att_mean) {
  __shared__ __align__(16) char smem[70656];
  u16* vs = (u16*)smem;                          // phase A: 128 x 264 shorts
  u16 (*Wbuf)[8192] = (u16(*)[8192])smem;        // phase B
  float* ostage = (float*)(smem + 32768);        // 2 x 4608 floats (128 x 36)
  float* boL = (float*)(smem + 69632);           // 256 floats

  const int t = threadIdx.x;
  const int w = t >> 6, lane = t & 63;
  const int col = lane & 31, hi5 = lane >> 5;
  const int r0 = blockIdx.x * 128;
  const int node = w * 32 + col;
  const int n = r0 + node;
  const int nl = (n < NN) ? n : (NN - 1);
  const bool valid = (n < NN);

  // ---- phase A: coalesced v load (slice-major, contiguous 8 KB chunks) ----
#pragma unroll
  for (int i = 0; i < 16; ++i) {
    int u = i * 256 + t;              // 0..4095 units of 16 B
    int sv = u >> 9, iu = u & 511;
    int nd = iu >> 2, dp = (iu & 3) * 8;
    int gn = r0 + nd; if (gn >= NN) gn = NN - 1;
    uint4 d = *(const uint4*)&v_bf[((size_t)sv * NN + gn) * 32 + dp];
    *(uint4*)&vs[nd * 264 + sv * 32 + dp] = d;
  }

  // ---- att[16] ----
  int b = batch[nl];
  float att[16];
#pragma unroll
  for (int q = 0; q < 4; ++q) {
    float4 sc = *(const float4*)(scores + (size_t)nl * 16 + q * 4);
    float4 mx = *(const float4*)(seg_max + b * 16 + q * 4);
    float4 sm = *(const float4*)(seg_sum + b * 16 + q * 4);
    att[q*4+0] = expf(sc.x - mx.x) / (sm.x + 1e-16f);
    att[q*4+1] = expf(sc.y - mx.y) / (sm.y + 1e-16f);
    att[q*4+2] = expf(sc.z - mx.z) / (sm.z + 1e-16f);
    att[q*4+3] = expf(sc.w - mx.w) / (sm.w + 1e-16f);
  }
  if (hi5 == 0 && valid) {
    float4 am;
    am.x = 0.25f * (att[0] + att[4] + att[8] + att[12]);
    am.y = 0.25f * (att[1] + att[5] + att[9] + att[13]);
    am.z = 0.25f * (att[2] + att[6] + att[10] + att[14]);
    am.w = 0.25f * (att[3] + att[7] + att[11] + att[15]);
    *(float4*)(att_mean + (size_t)n * 4) = am;
  }
  __syncthreads();                               // vs ready

  // ---- oaf from vs ----
  bf16x8 oaf[16];
#pragma unroll
  for (int dw = 0; dw < 4; ++dw) {
    float vr[4][8];
#pragma unroll
    for (int g = 0; g < 4; ++g) {
      uint4 u4 = *(const uint4*)&vs[node * 264 + g * 64 + dw * 16 + hi5 * 8];
      vr[g][0] = bflo(u4.x); vr[g][1] = bfhi(u4.x);
      vr[g][2] = bflo(u4.y); vr[g][3] = bfhi(u4.y);
      vr[g][4] = bflo(u4.z); vr[g][5] = bfhi(u4.z);
      vr[g][6] = bflo(u4.w); vr[g][7] = bfhi(u4.w);
    }
#pragma unroll
    for (int h = 0; h < 4; ++h) {
      unsigned res[4];
#pragma unroll
      for (int jj = 0; jj < 4; ++jj) {
        float lo = att[h*4+0]*vr[0][2*jj]   + att[h*4+1]*vr[1][2*jj] +
                   att[h*4+2]*vr[2][2*jj]   + att[h*4+3]*vr[3][2*jj];
        float hf = att[h*4+0]*vr[0][2*jj+1] + att[h*4+1]*vr[1][2*jj+1] +
                   att[h*4+2]*vr[2][2*jj+1] + att[h*4+3]*vr[3][2*jj+1];
        res[jj] = pack2(lo, hf);
      }
      uint4 u = {res[0], res[1], res[2], res[3]};
      oaf[h * 4 + dw] = *reinterpret_cast<bf16x8*>(&u);
    }
  }
  __syncthreads();                               // vs dead; overlay safe

  stage_slice(Wall, Wbuf[0], 24, w, lane);
  boL[t] = bo[t];
  __syncthreads();

  // ---- output GEMM: slices 24..31 with LDS-bounced coalesced stores ----
#pragma unroll
  for (int so = 0; so < 8; ++so) {
    if (so < 7) stage_slice(Wall, Wbuf[(so + 1) & 1], 25 + so, w, lane);
    f32x16 acc = gemm_lds(Wbuf[so & 1], oaf, lane);
    float* ob = ostage + (so & 1) * 4608;
#pragma unroll
    for (int q = 0; q < 4; ++q) {
      float4 b4 = *(const float4*)&boL[so * 32 + q * 8 + hi5 * 4];
      float4 o = {acc[4*q] + b4.x, acc[4*q+1] + b4.y,
                  acc[4*q+2] + b4.z, acc[4*q+3] + b4.w};
      *(float4*)&ob[node * 36 + q * 8 + hi5 * 4] = o;
    }
    __syncthreads();
#pragma unroll
    for (int i = 0; i < 4; ++i) {
      int u = i * 256 + t;            // 0..1023 units of 16 B
      int nd = u >> 3, part = u & 7;
      float4 d = *(const float4*)&ob[nd * 36 + part * 4];
      int gn = r0 + nd;
      if (gn < NN)
        *(float4*)&out[(size_t)gn * CC + so * 32 + part * 4] = d;
    }
  }
}

// ---------------------------------------------------------------------------
extern "C" void kernel_launch(void* const* d_in, const int* in_sizes, int n_in,
                              void* d_out, int out_size, void* d_ws, size_t ws_size,
                              hipStream_t stream) {
  const float* x  = (const float*)d_in[0];
  const int* batch = (const int*)d_in[1];
  const float* Wq = (const float*)d_in[2];
  const float* bq = (const float*)d_in[3];
  const float* Wk = (const float*)d_in[4];
  const float* bk = (const float*)d_in[5];
  const float* Wv = (const float*)d_in[6];
  const float* bv = (const float*)d_in[7];
  const float* Wo = (const float*)d_in[8];
  const float* bo = (const float*)d_in[9];

  char* ws = (char*)d_ws;
  u16*   Wall      = (u16*)ws;                               //   524,288 B
  int*   seg_start = (int*)(ws + 524288);                    //     2,052 B
  float* seg_max   = (float*)(ws + 528384);                  //    32,768 B
  float* seg_sum   = (float*)(ws + 561152);                  //    32,768 B
  float* scores    = (float*)(ws + 593920);                  // 12,800,000 B
  u16*   v_bf      = (u16*)(ws + 13393920);                  // 102,400,000 B (slice-major)

  float* out = (float*)d_out;
  float* att_mean = out + (size_t)NN * CC;

  const int NB = (NN + 127) / 128;   // 1563 blocks of 128 nodes

  prep_kernel<<<1024, 256, 0, stream>>>(Wq, Wk, Wv, Wo, Wall);
  seg_bounds_kernel<<<(NN + 255) / 256, 256, 0, stream>>>(batch, seg_start, NN);
  qkv_scores_kernel<<<NB, 256, 0, stream>>>(x, Wall, bq, bk, bv, v_bf, scores);
  seg_softmax_kernel<<<NG, 256, 0, stream>>>(scores, seg_start, seg_max, seg_sum);
  out_kernel<<<NB, 256, 0, stream>>>(v_bf, scores, batch, seg_max, seg_sum,
                                     Wall, bo, out, att_mean);
}